// Round 7
// baseline (23.667 us; speedup 1.0000x reference)
//
#include <hip/hip_runtime.h>
#include <math.h>

#define N_BINS 100
#define N_CAP  2

typedef float fvec4 __attribute__((ext_vector_type(4)));

__device__ __forceinline__ float sigmoidf(float x) {
    return 1.0f / (1.0f + expf(-x));
}

// One-shot kernel: each thread handles exactly 8 rows:
//   4 int4 index loads (issued upfront, 64B/lane), 16 LDS gathers,
//   2 float4 NON-TEMPORAL stores (32B/lane).
// NT stores keep the 32MiB output stream from churning L2/L3 so the 64MiB
// idx stream can stay Infinity-Cache-resident across graph replays.
__global__ __launch_bounds__(256) void RobotTrustModel_trust_kernel(
        const float* __restrict__ bin_centers,
        const float* __restrict__ pre_beta,
        const float* __restrict__ pre_can_l,
        const float* __restrict__ pre_can_u,
        const float* __restrict__ pre_will_l,
        const float* __restrict__ pre_will_u,
        const int4*  __restrict__ idx,
        fvec4*       __restrict__ out,
        int n_oct) {
    __shared__ float slut[N_CAP * N_BINS];

    int tid = threadIdx.x;
    int t   = blockIdx.x * blockDim.x + tid;

    // --- issue all four streaming loads immediately ---
    int4 v0 = make_int4(0,0,0,0), v1 = make_int4(0,0,0,0);
    int4 v2 = make_int4(0,0,0,0), v3 = make_int4(0,0,0,0);
    if (t < n_oct) {
        v0 = idx[4 * t + 0];
        v1 = idx[4 * t + 1];
        v2 = idx[4 * t + 2];
        v3 = idx[4 * t + 3];
    }

    // --- LUT compute (hidden under the loads above) ---
    if (tid < N_CAP * N_BINS) {
        int cap = tid / N_BINS;
        int bin = tid % N_BINS;

        float cl_raw = fminf(pre_can_l[cap], pre_can_u[cap]);
        float cu_raw = fmaxf(pre_can_l[cap], pre_can_u[cap]);
        float can_l = sigmoidf(cl_raw);
        float can_u = sigmoidf(cu_raw);

        float wl_raw = fminf(pre_will_l[0], pre_will_u[0]);
        float wu_raw = fmaxf(pre_will_l[0], pre_will_u[0]);
        float will = 0.5f * (sigmoidf(wl_raw) + sigmoidf(wu_raw));

        float beta  = pre_beta[cap] * pre_beta[cap];
        float denom = can_u - can_l;
        float p     = bin_centers[bin];

        float tt;
        if (beta < -50.0f) {
            tt = 1.0f - (1.0f / (beta * denom)) *
                 (log1pf(expf(beta * (p - can_l))) - log1pf(expf(beta * (p - can_u))));
        } else {
            tt = (p <= can_l) ? 1.0f
               : ((p > can_u) ? 0.0f
               : (can_u - p) / (denom + 1e-4f));
        }
        if (cap == 0) tt *= will;
        slut[cap * N_BINS + bin] = tt;
    }
    __syncthreads();

    if (t < n_oct) {
        fvec4 r0, r1;
        r0.x = slut[v0.x] * slut[N_BINS + v0.y];
        r0.y = slut[v0.z] * slut[N_BINS + v0.w];
        r0.z = slut[v1.x] * slut[N_BINS + v1.y];
        r0.w = slut[v1.z] * slut[N_BINS + v1.w];
        r1.x = slut[v2.x] * slut[N_BINS + v2.y];
        r1.y = slut[v2.z] * slut[N_BINS + v2.w];
        r1.z = slut[v3.x] * slut[N_BINS + v3.y];
        r1.w = slut[v3.z] * slut[N_BINS + v3.w];
        __builtin_nontemporal_store(r0, &out[2 * t + 0]);
        __builtin_nontemporal_store(r1, &out[2 * t + 1]);
    }
}

extern "C" void kernel_launch(void* const* d_in, const int* in_sizes, int n_in,
                              void* d_out, int out_size, void* d_ws, size_t ws_size,
                              hipStream_t stream) {
    const float* bin_centers = (const float*)d_in[0];
    const int*   obs_idx     = (const int*)d_in[1];
    const float* pre_beta    = (const float*)d_in[2];
    const float* pre_can_l   = (const float*)d_in[3];
    const float* pre_can_u   = (const float*)d_in[4];
    const float* pre_will_l  = (const float*)d_in[5];
    const float* pre_will_u  = (const float*)d_in[6];

    int n_diffs = in_sizes[1] / N_CAP;       // 8388608
    int n_oct   = n_diffs / 8;               // 1048576: 8 rows per thread
    int block   = 256;
    int grid    = (n_oct + block - 1) / block;   // 4096 blocks, one-shot

    RobotTrustModel_trust_kernel<<<grid, block, 0, stream>>>(
        bin_centers, pre_beta, pre_can_l, pre_can_u, pre_will_l, pre_will_u,
        (const int4*)obs_idx, (fvec4*)d_out, n_oct);
}

// Round 8
// 20.849 us; speedup vs baseline: 1.1352x; 1.1352x over previous
//
#include <hip/hip_runtime.h>
#include <math.h>

#define N_BINS 100
#define N_CAP  2

__device__ __forceinline__ float sigmoidf(float x) {
    return 1.0f / (1.0f + expf(-x));
}

// One-shot kernel (measured best, R4): each thread handles exactly 4 rows:
// 2 int4 index loads (32B/lane, adjacent), 8 LDS gathers, 1 float4 store
// (16B/lane). Grid sized so grid*block == n_diffs/4. Normal (cache-allocating)
// loads and stores — NT hints measured 14% slower (R6).
__global__ __launch_bounds__(256) void RobotTrustModel_trust_kernel(
        const float* __restrict__ bin_centers,
        const float* __restrict__ pre_beta,
        const float* __restrict__ pre_can_l,
        const float* __restrict__ pre_can_u,
        const float* __restrict__ pre_will_l,
        const float* __restrict__ pre_will_u,
        const int4*  __restrict__ idx,
        float4*      __restrict__ out,
        int n_quads) {
    __shared__ float slut[N_CAP * N_BINS];

    int tid = threadIdx.x;
    int t   = blockIdx.x * blockDim.x + tid;

    // --- issue both streaming loads immediately (preamble hides under them) ---
    int4 v0 = make_int4(0, 0, 0, 0), v1 = make_int4(0, 0, 0, 0);
    if (t < n_quads) {
        v0 = idx[2 * t];
        v1 = idx[2 * t + 1];
    }

    // --- LUT compute ---
    if (tid < N_CAP * N_BINS) {
        int cap = tid / N_BINS;
        int bin = tid % N_BINS;

        float cl_raw = fminf(pre_can_l[cap], pre_can_u[cap]);
        float cu_raw = fmaxf(pre_can_l[cap], pre_can_u[cap]);
        float can_l = sigmoidf(cl_raw);
        float can_u = sigmoidf(cu_raw);

        float wl_raw = fminf(pre_will_l[0], pre_will_u[0]);
        float wu_raw = fmaxf(pre_will_l[0], pre_will_u[0]);
        float will = 0.5f * (sigmoidf(wl_raw) + sigmoidf(wu_raw));

        float beta  = pre_beta[cap] * pre_beta[cap];
        float denom = can_u - can_l;
        float p     = bin_centers[bin];

        float tt;
        if (beta < -50.0f) {
            tt = 1.0f - (1.0f / (beta * denom)) *
                 (log1pf(expf(beta * (p - can_l))) - log1pf(expf(beta * (p - can_u))));
        } else {
            tt = (p <= can_l) ? 1.0f
               : ((p > can_u) ? 0.0f
               : (can_u - p) / (denom + 1e-4f));
        }
        if (cap == 0) tt *= will;
        slut[cap * N_BINS + bin] = tt;
    }
    __syncthreads();

    if (t < n_quads) {
        float4 r;
        r.x = slut[v0.x] * slut[N_BINS + v0.y];
        r.y = slut[v0.z] * slut[N_BINS + v0.w];
        r.z = slut[v1.x] * slut[N_BINS + v1.y];
        r.w = slut[v1.z] * slut[N_BINS + v1.w];
        out[t] = r;
    }
}

extern "C" void kernel_launch(void* const* d_in, const int* in_sizes, int n_in,
                              void* d_out, int out_size, void* d_ws, size_t ws_size,
                              hipStream_t stream) {
    const float* bin_centers = (const float*)d_in[0];
    const int*   obs_idx     = (const int*)d_in[1];
    const float* pre_beta    = (const float*)d_in[2];
    const float* pre_can_l   = (const float*)d_in[3];
    const float* pre_can_u   = (const float*)d_in[4];
    const float* pre_will_l  = (const float*)d_in[5];
    const float* pre_will_u  = (const float*)d_in[6];

    float* out = (float*)d_out;

    int n_diffs = in_sizes[1] / N_CAP;       // 8388608
    int n_quads = n_diffs / 4;               // 2097152: 4 rows per thread
    int block   = 256;
    int grid    = (n_quads + block - 1) / block;   // 8192 blocks, one-shot

    RobotTrustModel_trust_kernel<<<grid, block, 0, stream>>>(
        bin_centers, pre_beta, pre_can_l, pre_can_u, pre_will_l, pre_will_u,
        (const int4*)obs_idx, (float4*)out, n_quads);
}